// Round 1
// baseline (1653.613 us; speedup 1.0000x reference)
//
#include <hip/hip_runtime.h>

// MultiHeadedAttention fused forward, fp32 baseline.
// B=2, S=4096, D_MODEL=512, NH=8, D_K=64.
// Pipeline: [proj GEMM x3 -> Q/K/V per-head] -> [flash attention] -> [out GEMM].

#define S_LEN   4096
#define DM      512
#define NHEAD   8
#define DKH     64
#define NEG_BIG (-1e9f)
#define MINIT   (-3.402823466e38f)   // -FLT_MAX: avoids inf-inf NaN paths

// ---------------------------------------------------------------------------
// GEMM (NT): Y[r,c] = sum_k X[r,k] * W[c,k].  X:[M,512] W:[512,512].
// MODE 0: scatter to per-head layout Y[b][h][s][dk]  (h = c/64, dk = c%64)
// MODE 1: plain row-major Y[r*512 + c]  (final output projection)
// blockIdx.z selects which (X,W,Y) triple (q/k/v projections in one launch).
// 64x64 tile, BK=16, 256 threads, 4x4 outputs/thread.
// ---------------------------------------------------------------------------
template<int MODE>
__global__ __launch_bounds__(256)
void gemm_nt(const float* __restrict__ X0, const float* __restrict__ X1,
             const float* __restrict__ X2,
             const float* __restrict__ W0, const float* __restrict__ W1,
             const float* __restrict__ W2,
             float* __restrict__ Y0, float* __restrict__ Y1,
             float* __restrict__ Y2)
{
    const float *X, *W;
    float *Y;
    if (blockIdx.z == 0)      { X = X0; W = W0; Y = Y0; }
    else if (blockIdx.z == 1) { X = X1; W = W1; Y = Y1; }
    else                      { X = X2; W = W2; Y = Y2; }

    __shared__ float As[16][68];   // As[k][row], +4 pad keeps float4 alignment
    __shared__ float Bs[16][68];   // Bs[k][col]

    const int tid  = threadIdx.x;
    const int tx   = tid & 15;
    const int ty   = tid >> 4;
    const int row0 = blockIdx.x << 6;
    const int col0 = blockIdx.y << 6;
    const int lr   = tid >> 2;         // 0..63: tile row/col being staged
    const int lk   = (tid & 3) << 2;   // k-subsegment 0/4/8/12

    float acc[4][4] = {};

    for (int k0 = 0; k0 < DM; k0 += 16) {
        const float4 av = *(const float4*)&X[(size_t)(row0 + lr) * DM + k0 + lk];
        const float4 bv = *(const float4*)&W[(size_t)(col0 + lr) * DM + k0 + lk];
        __syncthreads();                       // prior iter's reads complete
        As[lk + 0][lr] = av.x; As[lk + 1][lr] = av.y;
        As[lk + 2][lr] = av.z; As[lk + 3][lr] = av.w;
        Bs[lk + 0][lr] = bv.x; Bs[lk + 1][lr] = bv.y;
        Bs[lk + 2][lr] = bv.z; Bs[lk + 3][lr] = bv.w;
        __syncthreads();
        #pragma unroll
        for (int kk = 0; kk < 16; ++kk) {
            const float4 a4 = *(const float4*)&As[kk][ty << 2];
            const float4 b4 = *(const float4*)&Bs[kk][tx << 2];
            const float a[4] = {a4.x, a4.y, a4.z, a4.w};
            const float b[4] = {b4.x, b4.y, b4.z, b4.w};
            #pragma unroll
            for (int i = 0; i < 4; ++i)
                #pragma unroll
                for (int j = 0; j < 4; ++j)
                    acc[i][j] = fmaf(a[i], b[j], acc[i][j]);
        }
    }

    if (MODE == 0) {
        const int h = col0 >> 6;  // 64-wide tiles align exactly with heads
        #pragma unroll
        for (int i = 0; i < 4; ++i) {
            const int r    = row0 + (ty << 2) + i;
            const int b    = r >> 12;     // / 4096
            const int srow = r & 4095;
            const float4 o4 = make_float4(acc[i][0], acc[i][1], acc[i][2], acc[i][3]);
            *(float4*)&Y[(((size_t)(b * NHEAD + h)) * S_LEN + srow) * DKH + (tx << 2)] = o4;
        }
    } else {
        #pragma unroll
        for (int i = 0; i < 4; ++i) {
            const int r = row0 + (ty << 2) + i;
            const float4 o4 = make_float4(acc[i][0], acc[i][1], acc[i][2], acc[i][3]);
            *(float4*)&Y[(size_t)r * DM + col0 + (tx << 2)] = o4;
        }
    }
}

// ---------------------------------------------------------------------------
// Flash-style masked attention, fp32.
// Block: one (b, h, 64-row q-tile). 256 threads, 4x4 outputs/thread.
// LDS: Qt[d][i] (transposed), KtPt union (Kt[d][j] during scores, Pt[j][i]
// during PV), Vs[j][d]. ~52 KB -> 3 blocks/CU.
// mask True -> score := -1e9 (exact reference semantics incl. fully-masked rows).
// ---------------------------------------------------------------------------
__global__ __launch_bounds__(256)
void attn_fwd(const float* __restrict__ Q, const float* __restrict__ K,
              const float* __restrict__ V, const int* __restrict__ mask,
              float* __restrict__ ctx)
{
    __shared__ float Qt[64][68];
    __shared__ float KtPt[64][68];
    __shared__ float Vs[64][68];

    const int tid = threadIdx.x;
    const int tx  = tid & 15;
    const int ty  = tid >> 4;
    const int h   = blockIdx.y;
    const int b   = blockIdx.z;
    const int q0  = blockIdx.x << 6;

    const float* Qb = Q + (size_t)(b * NHEAD + h) * S_LEN * DKH;
    const float* Kb = K + (size_t)(b * NHEAD + h) * S_LEN * DKH;
    const float* Vb = V + (size_t)(b * NHEAD + h) * S_LEN * DKH;
    const int*   Mb = mask + (size_t)b * S_LEN * S_LEN;

    const int li = tid >> 2;         // 0..63 row
    const int ld = (tid & 3) << 4;   // d-seg 0/16/32/48

    // Stage Q tile transposed: Qt[d][i] = Q[q0+i][d]
    #pragma unroll
    for (int c = 0; c < 4; ++c) {
        const int d = ld + (c << 2);
        const float4 qv = *(const float4*)&Qb[(size_t)(q0 + li) * DKH + d];
        Qt[d + 0][li] = qv.x; Qt[d + 1][li] = qv.y;
        Qt[d + 2][li] = qv.z; Qt[d + 3][li] = qv.w;
    }

    float m[4], l[4], o[4][4];
    #pragma unroll
    for (int i = 0; i < 4; ++i) {
        m[i] = MINIT; l[i] = 0.f;
        #pragma unroll
        for (int j = 0; j < 4; ++j) o[i][j] = 0.f;
    }

    for (int kt = 0; kt < S_LEN / 64; ++kt) {
        // prefetch K/V tile to regs (overlaps with waiting at barrier)
        const int krow = (kt << 6) + li;
        float4 kv[4], vv[4];
        #pragma unroll
        for (int c = 0; c < 4; ++c) {
            kv[c] = *(const float4*)&Kb[(size_t)krow * DKH + ld + (c << 2)];
            vv[c] = *(const float4*)&Vb[(size_t)krow * DKH + ld + (c << 2)];
        }
        __syncthreads();   // prev PV reads done (and Qt ready on iter 0)
        #pragma unroll
        for (int c = 0; c < 4; ++c) {
            const int d = ld + (c << 2);
            KtPt[d + 0][li] = kv[c].x; KtPt[d + 1][li] = kv[c].y;
            KtPt[d + 2][li] = kv[c].z; KtPt[d + 3][li] = kv[c].w;
            *(float4*)&Vs[li][d] = vv[c];
        }
        __syncthreads();

        // scores: s[i][j] = sum_d Qt[d][i]*Kt[d][j]
        float s[4][4] = {};
        #pragma unroll 16
        for (int d = 0; d < 64; ++d) {
            const float4 a4 = *(const float4*)&Qt[d][ty << 2];
            const float4 b4 = *(const float4*)&KtPt[d][tx << 2];
            const float a[4]  = {a4.x, a4.y, a4.z, a4.w};
            const float bq[4] = {b4.x, b4.y, b4.z, b4.w};
            #pragma unroll
            for (int i = 0; i < 4; ++i)
                #pragma unroll
                for (int j = 0; j < 4; ++j)
                    s[i][j] = fmaf(a[i], bq[j], s[i][j]);
        }

        // scale + mask (mask True -> -1e9, matching reference exactly)
        #pragma unroll
        for (int i = 0; i < 4; ++i) {
            const size_t mrow = (size_t)(q0 + (ty << 2) + i) * S_LEN;
            const int4 mv = *(const int4*)&Mb[mrow + (kt << 6) + (tx << 2)];
            s[i][0] = mv.x ? NEG_BIG : s[i][0] * 0.125f;
            s[i][1] = mv.y ? NEG_BIG : s[i][1] * 0.125f;
            s[i][2] = mv.z ? NEG_BIG : s[i][2] * 0.125f;
            s[i][3] = mv.w ? NEG_BIG : s[i][3] * 0.125f;
        }

        // online softmax: rows live in 16 lanes sharing ty (same wave)
        #pragma unroll
        for (int i = 0; i < 4; ++i) {
            float tmax = fmaxf(fmaxf(s[i][0], s[i][1]), fmaxf(s[i][2], s[i][3]));
            #pragma unroll
            for (int off = 8; off >= 1; off >>= 1)
                tmax = fmaxf(tmax, __shfl_xor(tmax, off, 16));
            const float newm  = fmaxf(m[i], tmax);
            const float alpha = __expf(m[i] - newm);
            float rsum = 0.f;
            #pragma unroll
            for (int j = 0; j < 4; ++j) {
                s[i][j] = __expf(s[i][j] - newm);
                rsum += s[i][j];
            }
            #pragma unroll
            for (int off = 8; off >= 1; off >>= 1)
                rsum += __shfl_xor(rsum, off, 16);
            l[i] = l[i] * alpha + rsum;
            m[i] = newm;
            #pragma unroll
            for (int j = 0; j < 4; ++j) o[i][j] *= alpha;
        }

        __syncthreads();   // all score reads of KtPt done before overwrite
        #pragma unroll
        for (int i = 0; i < 4; ++i)
            #pragma unroll
            for (int j = 0; j < 4; ++j)
                KtPt[(tx << 2) + j][(ty << 2) + i] = s[i][j];  // Pt[j][row]
        __syncthreads();

        // PV: o[i][jj] += sum_j Pt[j][row_i] * Vs[j][dk_jj]
        #pragma unroll 16
        for (int j = 0; j < 64; ++j) {
            const float4 p4 = *(const float4*)&KtPt[j][ty << 2];
            const float4 v4 = *(const float4*)&Vs[j][tx << 2];
            const float p[4]  = {p4.x, p4.y, p4.z, p4.w};
            const float vb[4] = {v4.x, v4.y, v4.z, v4.w};
            #pragma unroll
            for (int i = 0; i < 4; ++i)
                #pragma unroll
                for (int jj = 0; jj < 4; ++jj)
                    o[i][jj] = fmaf(p[i], vb[jj], o[i][jj]);
        }
    }

    // epilogue: normalize, write ctx in [B,S,512] so out-proj reads it plainly
    #pragma unroll
    for (int i = 0; i < 4; ++i) {
        const float inv = 1.f / l[i];
        const int r = q0 + (ty << 2) + i;
        const float4 o4 = make_float4(o[i][0] * inv, o[i][1] * inv,
                                      o[i][2] * inv, o[i][3] * inv);
        *(float4*)&ctx[((size_t)b * S_LEN + r) * DM + h * DKH + (tx << 2)] = o4;
    }
}

// ---------------------------------------------------------------------------
extern "C" void kernel_launch(void* const* d_in, const int* in_sizes, int n_in,
                              void* d_out, int out_size, void* d_ws, size_t ws_size,
                              hipStream_t stream)
{
    const float* q    = (const float*)d_in[0];
    const float* k    = (const float*)d_in[1];
    const float* v    = (const float*)d_in[2];
    const int*   mask = (const int*)d_in[3];   // bool mask as int32 per harness doc
    const float* Wq   = (const float*)d_in[4];
    const float* Wk   = (const float*)d_in[5];
    const float* Wv   = (const float*)d_in[6];
    const float* Wo   = (const float*)d_in[7];
    float* out = (float*)d_out;

    // workspace layout: Qh | Kh | Vh | ctx, each B*S*DM floats (16.78 MB)
    const size_t per = (size_t)2 * S_LEN * DM;   // 4,194,304 floats
    float* Qh  = (float*)d_ws;
    float* Kh  = Qh + per;
    float* Vh  = Kh + per;
    float* ctx = Vh + per;

    const dim3 blk(256);

    // Q/K/V projections in one launch (z selects matrix), per-head layout out
    gemm_nt<0><<<dim3(128, 8, 3), blk, 0, stream>>>(q, k, v, Wq, Wk, Wv, Qh, Kh, Vh);

    // flash attention: grid (q-tiles, heads, batch)
    attn_fwd<<<dim3(S_LEN / 64, NHEAD, 2), blk, 0, stream>>>(Qh, Kh, Vh, mask, ctx);

    // output projection
    gemm_nt<1><<<dim3(128, 8, 1), blk, 0, stream>>>(ctx, ctx, ctx, Wo, Wo, Wo,
                                                    out, out, out);
}

// Round 2
// 853.488 us; speedup vs baseline: 1.9375x; 1.9375x over previous
//
#include <hip/hip_runtime.h>

// MultiHeadedAttention: fp32 proj GEMMs (bf16 output) -> bf16 MFMA flash attn -> fp32 out GEMM.
// B=2, S=4096, D_MODEL=512, NH=8, D_K=64.

#define S_LEN   4096
#define DM      512
#define NHEAD   8
#define DKH     64
#define NEG_BIG (-1e9f)
#define MINIT   (-3.402823466e38f)

typedef __bf16 bf16x8 __attribute__((ext_vector_type(8)));
typedef __bf16 bf16x4 __attribute__((ext_vector_type(4)));
typedef float  f32x4  __attribute__((ext_vector_type(4)));

// ---------------------------------------------------------------------------
// QKV projection (NT): Y[r,c] = sum_k X[r,k]*W[c,k], fp32 compute, bf16 output
// scattered to per-head layout Y[b][h][s][dk]. z selects (q,Wq)/(k,Wk)/(v,Wv).
// Q (z==0) is pre-scaled by 1/sqrt(D_K) so attention skips the score scale.
// ---------------------------------------------------------------------------
__global__ __launch_bounds__(256)
void gemm_qkv(const float* __restrict__ X0, const float* __restrict__ X1,
              const float* __restrict__ X2,
              const float* __restrict__ W0, const float* __restrict__ W1,
              const float* __restrict__ W2,
              __bf16* __restrict__ Y0, __bf16* __restrict__ Y1,
              __bf16* __restrict__ Y2)
{
    const float *X, *W;
    __bf16 *Y;
    if (blockIdx.z == 0)      { X = X0; W = W0; Y = Y0; }
    else if (blockIdx.z == 1) { X = X1; W = W1; Y = Y1; }
    else                      { X = X2; W = W2; Y = Y2; }
    const float oscale = (blockIdx.z == 0) ? 0.125f : 1.0f;

    __shared__ float As[16][68];
    __shared__ float Bs[16][68];

    const int tid  = threadIdx.x;
    const int tx   = tid & 15;
    const int ty   = tid >> 4;
    const int row0 = blockIdx.x << 6;
    const int col0 = blockIdx.y << 6;
    const int lr   = tid >> 2;
    const int lk   = (tid & 3) << 2;

    float acc[4][4] = {};

    for (int k0 = 0; k0 < DM; k0 += 16) {
        const float4 av = *(const float4*)&X[(size_t)(row0 + lr) * DM + k0 + lk];
        const float4 bv = *(const float4*)&W[(size_t)(col0 + lr) * DM + k0 + lk];
        __syncthreads();
        As[lk + 0][lr] = av.x; As[lk + 1][lr] = av.y;
        As[lk + 2][lr] = av.z; As[lk + 3][lr] = av.w;
        Bs[lk + 0][lr] = bv.x; Bs[lk + 1][lr] = bv.y;
        Bs[lk + 2][lr] = bv.z; Bs[lk + 3][lr] = bv.w;
        __syncthreads();
        #pragma unroll
        for (int kk = 0; kk < 16; ++kk) {
            const float4 a4 = *(const float4*)&As[kk][ty << 2];
            const float4 b4 = *(const float4*)&Bs[kk][tx << 2];
            const float a[4] = {a4.x, a4.y, a4.z, a4.w};
            const float b[4] = {b4.x, b4.y, b4.z, b4.w};
            #pragma unroll
            for (int i = 0; i < 4; ++i)
                #pragma unroll
                for (int j = 0; j < 4; ++j)
                    acc[i][j] = fmaf(a[i], b[j], acc[i][j]);
        }
    }

    const int h = col0 >> 6;
    #pragma unroll
    for (int i = 0; i < 4; ++i) {
        const int r    = row0 + (ty << 2) + i;
        const int b    = r >> 12;
        const int srow = r & 4095;
        bf16x4 o4;
        o4[0] = (__bf16)(acc[i][0] * oscale);
        o4[1] = (__bf16)(acc[i][1] * oscale);
        o4[2] = (__bf16)(acc[i][2] * oscale);
        o4[3] = (__bf16)(acc[i][3] * oscale);
        *(bf16x4*)&Y[(((size_t)(b * NHEAD + h)) * S_LEN + srow) * DKH + (tx << 2)] = o4;
    }
}

// ---------------------------------------------------------------------------
// Output projection: fp32 NT GEMM, plain row-major out.
// ---------------------------------------------------------------------------
__global__ __launch_bounds__(256)
void gemm_out(const float* __restrict__ X, const float* __restrict__ W,
              float* __restrict__ Y)
{
    __shared__ float As[16][68];
    __shared__ float Bs[16][68];

    const int tid  = threadIdx.x;
    const int tx   = tid & 15;
    const int ty   = tid >> 4;
    const int row0 = blockIdx.x << 6;
    const int col0 = blockIdx.y << 6;
    const int lr   = tid >> 2;
    const int lk   = (tid & 3) << 2;

    float acc[4][4] = {};

    for (int k0 = 0; k0 < DM; k0 += 16) {
        const float4 av = *(const float4*)&X[(size_t)(row0 + lr) * DM + k0 + lk];
        const float4 bv = *(const float4*)&W[(size_t)(col0 + lr) * DM + k0 + lk];
        __syncthreads();
        As[lk + 0][lr] = av.x; As[lk + 1][lr] = av.y;
        As[lk + 2][lr] = av.z; As[lk + 3][lr] = av.w;
        Bs[lk + 0][lr] = bv.x; Bs[lk + 1][lr] = bv.y;
        Bs[lk + 2][lr] = bv.z; Bs[lk + 3][lr] = bv.w;
        __syncthreads();
        #pragma unroll
        for (int kk = 0; kk < 16; ++kk) {
            const float4 a4 = *(const float4*)&As[kk][ty << 2];
            const float4 b4 = *(const float4*)&Bs[kk][tx << 2];
            const float a[4] = {a4.x, a4.y, a4.z, a4.w};
            const float b[4] = {b4.x, b4.y, b4.z, b4.w};
            #pragma unroll
            for (int i = 0; i < 4; ++i)
                #pragma unroll
                for (int j = 0; j < 4; ++j)
                    acc[i][j] = fmaf(a[i], b[j], acc[i][j]);
        }
    }

    #pragma unroll
    for (int i = 0; i < 4; ++i) {
        const int r = row0 + (ty << 2) + i;
        const float4 o4 = make_float4(acc[i][0], acc[i][1], acc[i][2], acc[i][3]);
        *(float4*)&Y[(size_t)r * DM + col0 + (tx << 2)] = o4;
    }
}

// ---------------------------------------------------------------------------
// bf16 MFMA flash attention.
// Block: 512 threads = 8 waves, 128 q-rows (16/wave), KV tile 64.
// LDS (32 KB): Ks[64][64]bf16 | Vt[64d][64j]bf16 | Ps[128][64]bf16, all
// XOR-swizzled (byte ^= (row&7)<<4) to kill the 128B-row-stride 32-way
// bank conflict on ds_read_b128 (m214 pattern).
// mfma_f32_16x16x32_bf16 layouts: A/B: row|col = lane&15, k = (lane>>4)*8+i;
// C/D: col = lane&15, row = (lane>>4)*4 + reg.
// Q is pre-scaled by 0.125 in the projection; mask True -> score = -1e9.
// ---------------------------------------------------------------------------
__global__ __launch_bounds__(512, 4)
void attn_mfma(const __bf16* __restrict__ Q, const __bf16* __restrict__ K,
               const __bf16* __restrict__ V, const int* __restrict__ mask,
               float* __restrict__ ctx)
{
    __shared__ __align__(16) char lds[32768];
    char* Ks = lds;             // [64][64] bf16 (row = k-index j, col = d)
    char* Vt = lds + 8192;      // [64][64] bf16 (row = d, col = j)
    char* Ps = lds + 16384;     // [128][64] bf16 (row = q-row, col = j)

    const int tid  = threadIdx.x;
    const int lane = tid & 63;
    const int w    = tid >> 6;       // wave 0..7
    const int l15  = lane & 15;
    const int lhi  = lane >> 4;      // 0..3
    const int q0   = blockIdx.x << 7;
    const int h    = blockIdx.y;
    const int b    = blockIdx.z;

    const __bf16* Qb = Q + (size_t)(b * NHEAD + h) * S_LEN * DKH;
    const __bf16* Kb = K + (size_t)(b * NHEAD + h) * S_LEN * DKH;
    const __bf16* Vb = V + (size_t)(b * NHEAD + h) * S_LEN * DKH;
    const int*    Mb = mask + (size_t)b * S_LEN * S_LEN;

    // Q fragments (A-operand): row = l15 within wave's 16 rows, k-groups 0/32
    const int qrow = q0 + w * 16 + l15;
    const bf16x8 qa0 = *(const bf16x8*)&Qb[(size_t)qrow * DKH + lhi * 8];
    const bf16x8 qa1 = *(const bf16x8*)&Qb[(size_t)qrow * DKH + 32 + lhi * 8];

    f32x4 o[4];
    float m[4], l[4];
    #pragma unroll
    for (int r = 0; r < 4; ++r) {
        m[r] = MINIT; l[r] = 0.f;
        o[r] = (f32x4){0.f, 0.f, 0.f, 0.f};
    }

    // staging maps: K: thread -> (row j = tid>>3, 16B seg = tid&7), coalesced.
    // V: (j = tid&63, d-seg = tid>>6) so the 8 transpose b16-writes/thread are
    // spread across all 32 banks within each wave.
    const int kj   = tid >> 3;
    const int kseg = tid & 7;
    const int vj   = tid & 63;
    const int vd0  = (tid >> 6) * 8;

    for (int kt = 0; kt < S_LEN / 64; ++kt) {
        const int j0 = kt << 6;
        const uint4 kreg = *(const uint4*)&Kb[(size_t)(j0 + kj) * DKH + kseg * 8];
        const uint4 vreg = *(const uint4*)&Vb[(size_t)(j0 + vj) * DKH + vd0];

        __syncthreads();   // prior iter's Ks/Vt/Ps reads all complete
        {
            int off = kj * 128 + kseg * 16;
            off ^= (kj & 7) << 4;
            *(uint4*)(Ks + off) = kreg;
        }
        {
            const __bf16* vr = (const __bf16*)&vreg;
            #pragma unroll
            for (int i = 0; i < 8; ++i) {
                const int d = vd0 + i;
                int off = d * 128 + vj * 2;
                off ^= (d & 7) << 4;
                *(__bf16*)(Vt + off) = vr[i];
            }
        }
        __syncthreads();

        // ---- QK^T: wave computes S[16 x 64] as 4 col-tiles ----
        f32x4 s[4];
        #pragma unroll
        for (int t = 0; t < 4; ++t) {
            const int krow = t * 16 + l15;
            int off = krow * 128 + lhi * 16;
            off ^= (krow & 7) << 4;
            const bf16x8 kb0 = *(const bf16x8*)(Ks + off);
            const bf16x8 kb1 = *(const bf16x8*)(Ks + (off ^ 64));
            s[t] = (f32x4){0.f, 0.f, 0.f, 0.f};
            s[t] = __builtin_amdgcn_mfma_f32_16x16x32_bf16(qa0, kb0, s[t], 0, 0, 0);
            s[t] = __builtin_amdgcn_mfma_f32_16x16x32_bf16(qa1, kb1, s[t], 0, 0, 0);
        }

        // ---- mask + online softmax (rows r=0..3 of this lane group) ----
        #pragma unroll
        for (int r = 0; r < 4; ++r) {
            const int prow = w * 16 + lhi * 4 + r;           // q-row in block
            const size_t mbase = (size_t)(q0 + prow) * S_LEN + j0 + l15;
            float sv[4];
            #pragma unroll
            for (int t = 0; t < 4; ++t)
                sv[t] = Mb[mbase + t * 16] ? NEG_BIG : s[t][r];

            float tmax = fmaxf(fmaxf(sv[0], sv[1]), fmaxf(sv[2], sv[3]));
            #pragma unroll
            for (int d = 8; d >= 1; d >>= 1)
                tmax = fmaxf(tmax, __shfl_xor(tmax, d, 16));
            const float newm  = fmaxf(m[r], tmax);
            const float alpha = __expf(m[r] - newm);
            float rsum = 0.f;
            #pragma unroll
            for (int t = 0; t < 4; ++t) {
                sv[t] = __expf(sv[t] - newm);
                rsum += sv[t];
            }
            #pragma unroll
            for (int d = 8; d >= 1; d >>= 1)
                rsum += __shfl_xor(rsum, d, 16);
            l[r] = l[r] * alpha + rsum;
            m[r] = newm;
            o[0][r] *= alpha; o[1][r] *= alpha;
            o[2][r] *= alpha; o[3][r] *= alpha;

            #pragma unroll
            for (int t = 0; t < 4; ++t) {
                int off = prow * 128 + (t * 16 + l15) * 2;
                off ^= (prow & 7) << 4;
                *(__bf16*)(Ps + off) = (__bf16)sv[t];
            }
        }
        __syncthreads();   // Ps visible to whole wave's reads

        // ---- PV: O[16 x 64] += P[16 x 64] * V[64 x 64] ----
        {
            const int parow = w * 16 + l15;
            int poff = parow * 128 + lhi * 16;
            poff ^= (parow & 7) << 4;
            const bf16x8 pa0 = *(const bf16x8*)(Ps + poff);
            const bf16x8 pa1 = *(const bf16x8*)(Ps + (poff ^ 64));
            #pragma unroll
            for (int dt = 0; dt < 4; ++dt) {
                const int vrow = dt * 16 + l15;
                int voff = vrow * 128 + lhi * 16;
                voff ^= (vrow & 7) << 4;
                const bf16x8 vb0 = *(const bf16x8*)(Vt + voff);
                const bf16x8 vb1 = *(const bf16x8*)(Vt + (voff ^ 64));
                o[dt] = __builtin_amdgcn_mfma_f32_16x16x32_bf16(pa0, vb0, o[dt], 0, 0, 0);
                o[dt] = __builtin_amdgcn_mfma_f32_16x16x32_bf16(pa1, vb1, o[dt], 0, 0, 0);
            }
        }
    }

    // epilogue: normalize, scatter to ctx [B,S,512] fp32
    #pragma unroll
    for (int r = 0; r < 4; ++r) {
        const float inv = 1.f / l[r];
        const size_t row = (size_t)b * S_LEN + q0 + w * 16 + lhi * 4 + r;
        float* dst = ctx + row * DM + h * DKH + l15;
        dst[0]  = o[0][r] * inv;
        dst[16] = o[1][r] * inv;
        dst[32] = o[2][r] * inv;
        dst[48] = o[3][r] * inv;
    }
}

// ---------------------------------------------------------------------------
extern "C" void kernel_launch(void* const* d_in, const int* in_sizes, int n_in,
                              void* d_out, int out_size, void* d_ws, size_t ws_size,
                              hipStream_t stream)
{
    const float* q    = (const float*)d_in[0];
    const float* k    = (const float*)d_in[1];
    const float* v    = (const float*)d_in[2];
    const int*   mask = (const int*)d_in[3];
    const float* Wq   = (const float*)d_in[4];
    const float* Wk   = (const float*)d_in[5];
    const float* Wv   = (const float*)d_in[6];
    const float* Wo   = (const float*)d_in[7];
    float* out = (float*)d_out;

    // ws: Qh|Kh|Vh bf16 per-head [2][8][4096][64] (8 MB each), ctx fp32 (16 MB)
    const size_t per = (size_t)2 * S_LEN * DM;   // 4,194,304 elements
    __bf16* Qh = (__bf16*)d_ws;
    __bf16* Kh = Qh + per;
    __bf16* Vh = Kh + per;
    float*  ctx = (float*)(Vh + per);

    gemm_qkv<<<dim3(128, 8, 3), dim3(256), 0, stream>>>(q, k, v, Wq, Wk, Wv,
                                                        Qh, Kh, Vh);

    attn_mfma<<<dim3(S_LEN / 128, NHEAD, 2), dim3(512), 0, stream>>>(
        Qh, Kh, Vh, mask, ctx);

    gemm_out<<<dim3(128, 8, 1), dim3(256), 0, stream>>>(ctx, Wo, out);
}

// Round 3
// 436.575 us; speedup vs baseline: 3.7877x; 1.9550x over previous
//
#include <hip/hip_runtime.h>

// MultiHeadedAttention, all-bf16-MFMA pipeline.
// pack_mask (ballot bitpack) -> gemm_bf16<0> QKV proj -> attn (swapped-QKT
// in-register softmax flash) -> gemm_bf16<1> out proj.
// B=2, S=4096, D_MODEL=512, NH=8, D_K=64.

#define S_LEN   4096
#define DM      512
#define NHEAD   8
#define DKH     64
#define NEG_BIG (-1e9f)
#define MINIT   (-3.402823466e38f)

typedef __bf16 bf16x8 __attribute__((ext_vector_type(8)));
typedef __bf16 bf16x4 __attribute__((ext_vector_type(4)));
typedef float  f32x4  __attribute__((ext_vector_type(4)));
typedef unsigned long long u64;

__device__ inline uint4 cvt8(float4 a, float4 b) {
    union { bf16x8 v; uint4 u; } c;
    c.v[0] = (__bf16)a.x; c.v[1] = (__bf16)a.y;
    c.v[2] = (__bf16)a.z; c.v[3] = (__bf16)a.w;
    c.v[4] = (__bf16)b.x; c.v[5] = (__bf16)b.y;
    c.v[6] = (__bf16)b.z; c.v[7] = (__bf16)b.w;
    return c.u;
}

// ---------------------------------------------------------------------------
// Mask bitpack: one bit per mask int, word w covers flat ints [64w, 64w+64).
// ---------------------------------------------------------------------------
__global__ __launch_bounds__(256)
void pack_mask(const int* __restrict__ m, u64* __restrict__ bits)
{
    const size_t i = (size_t)blockIdx.x * 256 + threadIdx.x;
    const u64 b = __ballot(m[i] != 0);
    if ((threadIdx.x & 63) == 0) bits[i >> 6] = b;
}

// ---------------------------------------------------------------------------
// bf16 MFMA GEMM (NT): Y[r,c] = sum_k X[r,k]*W[c,k].
// 512 thr = 8 waves (2x4), tile 128x128, BK=64. LDS 32KB XOR-swizzled.
// MODE 0: X fp32, W fp32, out bf16 scattered per-head [b][h][s][dk];
//         z selects q/k/v triple; z==0 folds the 1/sqrt(d_k)=0.125 scale.
// MODE 1: X bf16 (ctx), W fp32, out fp32 row-major.
// ---------------------------------------------------------------------------
template<int MODE>
__global__ __launch_bounds__(512, 4)
void gemm_bf16(const void* __restrict__ Xv0, const void* __restrict__ Xv1,
               const void* __restrict__ Xv2,
               const float* __restrict__ W0, const float* __restrict__ W1,
               const float* __restrict__ W2,
               void* __restrict__ Yv0, void* __restrict__ Yv1,
               void* __restrict__ Yv2)
{
    const void* Xv; const float* W; void* Yv;
    if (blockIdx.z == 0)      { Xv = Xv0; W = W0; Yv = Yv0; }
    else if (blockIdx.z == 1) { Xv = Xv1; W = W1; Yv = Yv1; }
    else                      { Xv = Xv2; W = W2; Yv = Yv2; }
    const float oscale = (MODE == 0 && blockIdx.z == 0) ? 0.125f : 1.0f;

    __shared__ __align__(16) char lds[32768];
    char* Xs = lds;            // [128][64] bf16, 16B-block XOR swizzle
    char* Ws = lds + 16384;

    const int tid  = threadIdx.x;
    const int lane = tid & 63;
    const int l15  = lane & 15;
    const int lhi  = lane >> 4;
    const int w    = tid >> 6;
    const int wr   = w >> 2;          // 0..1: 64-row half
    const int wc   = w & 3;           // 0..3: 32-col quarter
    const int row0 = blockIdx.x << 7;
    const int col0 = blockIdx.y << 7;

    const int sr = tid >> 2;          // staging row 0..127
    const int sc = (tid & 3) << 1;    // staging slot pair base (0/2/4/6)

    f32x4 acc[4][2];
    #pragma unroll
    for (int m = 0; m < 4; ++m)
        #pragma unroll
        for (int n = 0; n < 2; ++n)
            acc[m][n] = (f32x4){0.f, 0.f, 0.f, 0.f};

    for (int k0 = 0; k0 < DM; k0 += 64) {
        uint4 xa, xb, wa, wb;
        if (MODE == 0) {
            const float* X = (const float*)Xv;
            const size_t base = (size_t)(row0 + sr) * DM + k0 + sc * 8;
            const float4 x0 = *(const float4*)&X[base];
            const float4 x1 = *(const float4*)&X[base + 4];
            const float4 x2 = *(const float4*)&X[base + 8];
            const float4 x3 = *(const float4*)&X[base + 12];
            xa = cvt8(x0, x1); xb = cvt8(x2, x3);
        } else {
            const __bf16* X = (const __bf16*)Xv;
            const size_t base = (size_t)(row0 + sr) * DM + k0 + sc * 8;
            xa = *(const uint4*)&X[base];
            xb = *(const uint4*)&X[base + 8];
        }
        {
            const size_t base = (size_t)(col0 + sr) * DM + k0 + sc * 8;
            const float4 w0_ = *(const float4*)&W[base];
            const float4 w1_ = *(const float4*)&W[base + 4];
            const float4 w2_ = *(const float4*)&W[base + 8];
            const float4 w3_ = *(const float4*)&W[base + 12];
            wa = cvt8(w0_, w1_); wb = cvt8(w2_, w3_);
        }
        __syncthreads();
        *(uint4*)(Xs + sr * 128 + ((sc       ^ (sr & 7)) << 4)) = xa;
        *(uint4*)(Xs + sr * 128 + (((sc + 1) ^ (sr & 7)) << 4)) = xb;
        *(uint4*)(Ws + sr * 128 + ((sc       ^ (sr & 7)) << 4)) = wa;
        *(uint4*)(Ws + sr * 128 + (((sc + 1) ^ (sr & 7)) << 4)) = wb;
        __syncthreads();

        #pragma unroll
        for (int kk = 0; kk < 2; ++kk) {
            bf16x8 af[4], bfr[2];
            #pragma unroll
            for (int m = 0; m < 4; ++m) {
                const int r = wr * 64 + m * 16 + l15;
                af[m] = *(const bf16x8*)(Xs + r * 128 + ((((kk << 2) + lhi) ^ (r & 7)) << 4));
            }
            #pragma unroll
            for (int n = 0; n < 2; ++n) {
                const int r = wc * 32 + n * 16 + l15;
                bfr[n] = *(const bf16x8*)(Ws + r * 128 + ((((kk << 2) + lhi) ^ (r & 7)) << 4));
            }
            #pragma unroll
            for (int m = 0; m < 4; ++m)
                #pragma unroll
                for (int n = 0; n < 2; ++n)
                    acc[m][n] = __builtin_amdgcn_mfma_f32_16x16x32_bf16(af[m], bfr[n], acc[m][n], 0, 0, 0);
        }
    }

    // epilogue: C/D layout col=l15, row=lhi*4+r
    #pragma unroll
    for (int m = 0; m < 4; ++m) {
        #pragma unroll
        for (int n = 0; n < 2; ++n) {
            #pragma unroll
            for (int r = 0; r < 4; ++r) {
                const int row = row0 + wr * 64 + m * 16 + lhi * 4 + r;
                const int col = col0 + wc * 32 + n * 16 + l15;
                if (MODE == 0) {
                    const int b = row >> 12, srow = row & 4095;
                    const int h = col >> 6,  dk = col & 63;
                    ((__bf16*)Yv)[(((size_t)(b * NHEAD + h)) * S_LEN + srow) * DKH + dk] =
                        (__bf16)(acc[m][n][r] * oscale);
                } else {
                    ((float*)Yv)[(size_t)row * DM + col] = acc[m][n][r];
                }
            }
        }
    }
}

// ---------------------------------------------------------------------------
// Flash attention, swapped-operand MFMA, in-register softmax.
// 512 thr = 8 waves, 128 q-rows/block (16/wave), KV tile 64.
// Each lane owns ONE q-row (q = l15) and 16 of its 64 scores per tile
// (k = t*16 + lhi*4 + r). Row max/sum: 15 in-lane ops + shfl_xor(16,32).
// QKT: s = mfma(K_frag, Q_frag) -> S^T. PV: o = mfma(Vt_frag, P_frag) -> O^T.
// P redistribution to B-frag layout via per-wave-private LDS (no barrier).
// Mask from bit-packed words (1 u64 load/lane/tile). Defer-max THR=8.
// ---------------------------------------------------------------------------
__global__ __launch_bounds__(512, 4)
void attn_mfma(const __bf16* __restrict__ Q, const __bf16* __restrict__ K,
               const __bf16* __restrict__ V, const u64* __restrict__ bits,
               __bf16* __restrict__ ctx)
{
    __shared__ __align__(16) char lds[32768];
    char* Ks = lds;             // [64][64] bf16 (row j, col d), swizzled
    char* Vt = lds + 8192;      // [64][64] bf16 (row d, col j), swizzled
    char* Ps = lds + 16384;     // per-wave [16 q][64 k] bf16, swizzled

    const int tid  = threadIdx.x;
    const int lane = tid & 63;
    const int w    = tid >> 6;
    const int l15  = lane & 15;
    const int lhi  = lane >> 4;
    const int q0   = blockIdx.x << 7;
    const int h    = blockIdx.y;
    const int b    = blockIdx.z;

    const __bf16* Qb = Q + (size_t)(b * NHEAD + h) * S_LEN * DKH;
    const __bf16* Kb = K + (size_t)(b * NHEAD + h) * S_LEN * DKH;
    const __bf16* Vb = V + (size_t)(b * NHEAD + h) * S_LEN * DKH;

    const int qrow = q0 + w * 16 + l15;                  // this lane's q-row
    const u64* Mb = bits + (size_t)b * (S_LEN * (S_LEN / 64)) + (size_t)qrow * 64;

    // Q B-operand fragments (col=l15=q, k(d)=lhi*8+i), d-halves 0/32
    const bf16x8 qa0 = *(const bf16x8*)&Qb[(size_t)qrow * DKH + lhi * 8];
    const bf16x8 qa1 = *(const bf16x8*)&Qb[(size_t)qrow * DKH + 32 + lhi * 8];

    char* psb = Ps + w * 2048;   // per-wave private P scratch

    f32x4 o[4];
    float m_r = MINIT, l_r = 0.f;
    #pragma unroll
    for (int dt = 0; dt < 4; ++dt) o[dt] = (f32x4){0.f, 0.f, 0.f, 0.f};

    const int kj   = tid >> 3;        // K staging: row
    const int kseg = tid & 7;         //            16B slot
    const int vj   = tid & 63;        // V staging: source row j
    const int vd0  = (tid >> 6) * 8;  //            d-segment

    for (int kt = 0; kt < S_LEN / 64; ++kt) {
        const int j0 = kt << 6;
        const uint4 kreg = *(const uint4*)&Kb[(size_t)(j0 + kj) * DKH + kseg * 8];
        const uint4 vreg = *(const uint4*)&Vb[(size_t)(j0 + vj) * DKH + vd0];
        const u64   mw   = Mb[kt];

        __syncthreads();   // prior iter's Ks/Vt reads complete
        *(uint4*)(Ks + kj * 128 + ((kseg ^ (kj & 7)) << 4)) = kreg;
        {
            const __bf16* vr = (const __bf16*)&vreg;
            #pragma unroll
            for (int i = 0; i < 8; ++i) {
                const int d = vd0 + i;
                int off = d * 128 + vj * 2;
                off ^= (d & 7) << 4;
                *(__bf16*)(Vt + off) = vr[i];
            }
        }
        __syncthreads();

        // ---- QK^T (swapped): s[t] = S^T tile rows t*16..+15, col q=l15 ----
        f32x4 s[4];
        #pragma unroll
        for (int t = 0; t < 4; ++t) {
            const int krow = t * 16 + l15;
            const int off = krow * 128 + ((lhi ^ (krow & 7)) << 4);
            const bf16x8 kb0 = *(const bf16x8*)(Ks + off);
            const bf16x8 kb1 = *(const bf16x8*)(Ks + (off ^ 64));
            f32x4 z = (f32x4){0.f, 0.f, 0.f, 0.f};
            z = __builtin_amdgcn_mfma_f32_16x16x32_bf16(kb0, qa0, z, 0, 0, 0);
            s[t] = __builtin_amdgcn_mfma_f32_16x16x32_bf16(kb1, qa1, z, 0, 0, 0);
        }

        // ---- mask + in-register online softmax (lane owns q-row l15) ----
        const unsigned int lo = (unsigned int)mw, hi = (unsigned int)(mw >> 32);
        unsigned int shf[4];
        shf[0] = lo >> (lhi << 2);
        shf[1] = lo >> (16 + (lhi << 2));
        shf[2] = hi >> (lhi << 2);
        shf[3] = hi >> (16 + (lhi << 2));

        float pv[4][4];
        #pragma unroll
        for (int t = 0; t < 4; ++t)
            #pragma unroll
            for (int r = 0; r < 4; ++r)
                pv[t][r] = ((shf[t] >> r) & 1) ? NEG_BIG : s[t][r];

        float tmax = pv[0][0];
        #pragma unroll
        for (int t = 0; t < 4; ++t)
            #pragma unroll
            for (int r = 0; r < 4; ++r)
                tmax = fmaxf(tmax, pv[t][r]);
        tmax = fmaxf(tmax, __shfl_xor(tmax, 16));
        tmax = fmaxf(tmax, __shfl_xor(tmax, 32));

        // defer-max: only rescale when the running max grew by > 8
        if (!__all(tmax <= m_r + 8.f)) {
            const float newm  = fmaxf(m_r, tmax);
            const float alpha = __expf(m_r - newm);
            m_r = newm;
            l_r *= alpha;
            #pragma unroll
            for (int dt = 0; dt < 4; ++dt) {
                o[dt][0] *= alpha; o[dt][1] *= alpha;
                o[dt][2] *= alpha; o[dt][3] *= alpha;
            }
        }

        float rsum = 0.f;
        #pragma unroll
        for (int t = 0; t < 4; ++t)
            #pragma unroll
            for (int r = 0; r < 4; ++r) {
                pv[t][r] = __expf(pv[t][r] - m_r);
                rsum += pv[t][r];
            }
        rsum += __shfl_xor(rsum, 16);
        rsum += __shfl_xor(rsum, 32);
        l_r += rsum;

        // ---- P -> bf16, per-wave LDS scratch (wave-private: no barrier) ----
        #pragma unroll
        for (int t = 0; t < 4; ++t)
            #pragma unroll
            for (int c = 0; c < 2; ++c) {
                union { __bf16 h2[2]; unsigned int u; } pk;
                pk.h2[0] = (__bf16)pv[t][2 * c];
                pk.h2[1] = (__bf16)pv[t][2 * c + 1];
                const int kbyte = t * 32 + (lhi << 3) + (c << 2);   // k*2
                const int off = l15 * 128
                              + (((kbyte >> 4) ^ (l15 & 7)) << 4) + (kbyte & 15);
                *(unsigned int*)(psb + off) = pk.u;
            }
        const int poff = l15 * 128 + ((lhi ^ (l15 & 7)) << 4);
        const bf16x8 pb0 = *(const bf16x8*)(psb + poff);
        const bf16x8 pb1 = *(const bf16x8*)(psb + (poff ^ 64));

        // ---- PV (swapped): o[dt] = O^T tile, rows d=dt*16..+15, col q=l15 ----
        #pragma unroll
        for (int dt = 0; dt < 4; ++dt) {
            const int vrow = dt * 16 + l15;
            const int voff = vrow * 128 + ((lhi ^ (vrow & 7)) << 4);
            const bf16x8 vb0 = *(const bf16x8*)(Vt + voff);
            const bf16x8 vb1 = *(const bf16x8*)(Vt + (voff ^ 64));
            o[dt] = __builtin_amdgcn_mfma_f32_16x16x32_bf16(vb0, pb0, o[dt], 0, 0, 0);
            o[dt] = __builtin_amdgcn_mfma_f32_16x16x32_bf16(vb1, pb1, o[dt], 0, 0, 0);
        }
    }

    // epilogue: O[q=l15][d = dt*16 + lhi*4 + r] -> ctx bf16 [B,S,512]
    const float inv = 1.f / l_r;
    #pragma unroll
    for (int dt = 0; dt < 4; ++dt) {
        bf16x4 ov;
        ov[0] = (__bf16)(o[dt][0] * inv);
        ov[1] = (__bf16)(o[dt][1] * inv);
        ov[2] = (__bf16)(o[dt][2] * inv);
        ov[3] = (__bf16)(o[dt][3] * inv);
        *(bf16x4*)&ctx[((size_t)b * S_LEN + qrow) * DM + h * DKH + dt * 16 + lhi * 4] = ov;
    }
}

// ---------------------------------------------------------------------------
extern "C" void kernel_launch(void* const* d_in, const int* in_sizes, int n_in,
                              void* d_out, int out_size, void* d_ws, size_t ws_size,
                              hipStream_t stream)
{
    const float* q    = (const float*)d_in[0];
    const float* k    = (const float*)d_in[1];
    const float* v    = (const float*)d_in[2];
    const int*   mask = (const int*)d_in[3];
    const float* Wq   = (const float*)d_in[4];
    const float* Wk   = (const float*)d_in[5];
    const float* Wv   = (const float*)d_in[6];
    const float* Wo   = (const float*)d_in[7];
    float* out = (float*)d_out;

    // ws: Qh|Kh|Vh|ctx bf16 (8 MB each) | mask bits u64 (4 MB) = 36 MB
    const size_t per = (size_t)2 * S_LEN * DM;
    __bf16* Qh  = (__bf16*)d_ws;
    __bf16* Kh  = Qh + per;
    __bf16* Vh  = Kh + per;
    __bf16* ctx = Vh + per;
    u64*    bits = (u64*)(ctx + per);

    pack_mask<<<dim3((2 * S_LEN * S_LEN) / 256), dim3(256), 0, stream>>>(mask, bits);

    gemm_bf16<0><<<dim3(64, 4, 3), dim3(512), 0, stream>>>(
        q, k, v, Wq, Wk, Wv, Qh, Kh, Vh);

    attn_mfma<<<dim3(S_LEN / 128, NHEAD, 2), dim3(512), 0, stream>>>(
        Qh, Kh, Vh, bits, ctx);

    gemm_bf16<1><<<dim3(64, 4, 1), dim3(512), 0, stream>>>(
        ctx, ctx, ctx, Wo, Wo, Wo, out, out, out);
}

// Round 6
// 420.369 us; speedup vs baseline: 3.9337x; 1.0386x over previous
//
#include <hip/hip_runtime.h>

// MultiHeadedAttention, all-bf16-MFMA pipeline.
// cast_w -> pack_mask -> gemm<0> QKV (global_load_lds W, vector epilogue)
// -> attn (dbuf K/V, 1 barrier/tile, setprio) -> gemm<1> out proj.
// B=2, S=4096, D_MODEL=512, NH=8, D_K=64.

#define S_LEN   4096
#define DM      512
#define NHEAD   8
#define DKH     64
#define NT      (S_LEN / 64)
#define NEG_BIG (-1e9f)
#define MINIT   (-3.402823466e38f)

typedef __bf16 bf16x8 __attribute__((ext_vector_type(8)));
typedef __bf16 bf16x4 __attribute__((ext_vector_type(4)));
typedef float  f32x4  __attribute__((ext_vector_type(4)));
typedef unsigned long long u64;

// async global->LDS, 16B per lane; lds dest = wave-uniform base + lane*16
__device__ inline void gload_lds16(const void* g, void* l) {
    __builtin_amdgcn_global_load_lds(
        (const __attribute__((address_space(1))) unsigned int*)g,
        (__attribute__((address_space(3))) unsigned int*)l, 16, 0, 0);
}

__device__ inline uint4 cvt8(float4 a, float4 b) {
    union { bf16x8 v; uint4 u; } c;
    c.v[0] = (__bf16)a.x; c.v[1] = (__bf16)a.y;
    c.v[2] = (__bf16)a.z; c.v[3] = (__bf16)a.w;
    c.v[4] = (__bf16)b.x; c.v[5] = (__bf16)b.y;
    c.v[6] = (__bf16)b.z; c.v[7] = (__bf16)b.w;
    return c.u;
}

// ---------------------------------------------------------------------------
// Weight pre-cast: [Wq|Wk|Wv|Wo] fp32 -> bf16 (4 x 262144 elems).
// ---------------------------------------------------------------------------
__global__ __launch_bounds__(256)
void cast_w(const float* __restrict__ Wq, const float* __restrict__ Wk,
            const float* __restrict__ Wv, const float* __restrict__ Wo,
            __bf16* __restrict__ out)
{
    const int t = blockIdx.x * 256 + threadIdx.x;   // 131072 threads
    const int e = t * 8;
    const int z = e >> 18;
    const int i = e & 262143;
    const float* W = (z == 0) ? Wq : (z == 1) ? Wk : (z == 2) ? Wv : Wo;
    const float4 a = *(const float4*)&W[i];
    const float4 b = *(const float4*)&W[i + 4];
    *(uint4*)&out[e] = cvt8(a, b);
}

// ---------------------------------------------------------------------------
// Mask bitpack: one bit per int; word w covers flat ints [64w, 64w+64).
// ---------------------------------------------------------------------------
__global__ __launch_bounds__(256)
void pack_mask(const int* __restrict__ m, u64* __restrict__ bits)
{
    const size_t i = (size_t)blockIdx.x * 256 + threadIdx.x;
    const u64 b = __ballot(m[i] != 0);
    if ((threadIdx.x & 63) == 0) bits[i >> 6] = b;
}

// ---------------------------------------------------------------------------
// bf16 MFMA GEMM (NT): Y[r,c] = sum_k X[r,k]*W[c,k]. Swapped operands:
// acc = mfma(A=Wfrag, B=Xfrag) -> lane holds row r=l15, 4 consecutive c.
// 512 thr = 8 waves (2 row-halves x 4 col-quarters), tile 128x128, BK=64.
// W staged via global_load_lds (pre-swizzled source). MODE 0: X fp32
// reg-staged+cvt, out bf16 per-head scatter (z=q/k/v, q folds 0.125).
// MODE 1: X bf16 via global_load_lds, out fp32 row-major float4.
// ---------------------------------------------------------------------------
template<int MODE>
__global__ __launch_bounds__(512, 4)
void gemm_mfma(const float* __restrict__ X0, const float* __restrict__ X1,
               const float* __restrict__ X2, const __bf16* __restrict__ Xb,
               const __bf16* __restrict__ Wb,
               __bf16* __restrict__ Y0, __bf16* __restrict__ Y1,
               __bf16* __restrict__ Y2, float* __restrict__ Yf)
{
    __shared__ __align__(16) char lds[32768];
    char* Xs = lds;            // [128 r][64 k] bf16, 16B-slot XOR swizzle
    char* Ws = lds + 16384;    // [128 c][64 k]

    const int tid  = threadIdx.x;
    const int lane = tid & 63;
    const int l15  = lane & 15;
    const int lhi  = lane >> 4;
    const int w    = tid >> 6;
    const int wr   = w >> 2;
    const int wc   = w & 3;
    const int row0 = blockIdx.x << 7;
    const int col0 = blockIdx.y << 7;
    const int z    = blockIdx.z;

    const float*  Xf = (z == 0) ? X0 : (z == 1) ? X1 : X2;
    __bf16*       Yb = (z == 0) ? Y0 : (z == 1) ? Y1 : Y2;
    const __bf16* W  = Wb + (size_t)(MODE == 0 ? z : 0) * DM * DM;

    const int sr = tid >> 2;          // MODE0 X staging row
    const int sc = (tid & 3) << 1;    // slot pair

    f32x4 acc[4][2];
    #pragma unroll
    for (int m = 0; m < 4; ++m)
        #pragma unroll
        for (int n = 0; n < 2; ++n)
            acc[m][n] = (f32x4){0.f, 0.f, 0.f, 0.f};

    for (int k0 = 0; k0 < DM; k0 += 64) {
        uint4 xa, xb2;
        if (MODE == 0) {
            const size_t base = (size_t)(row0 + sr) * DM + k0 + sc * 8;
            const float4 a0 = *(const float4*)&Xf[base];
            const float4 a1 = *(const float4*)&Xf[base + 4];
            const float4 a2 = *(const float4*)&Xf[base + 8];
            const float4 a3 = *(const float4*)&Xf[base + 12];
            xa = cvt8(a0, a1); xb2 = cvt8(a2, a3);
        }
        __syncthreads();                   // prev iter's fragment reads done
        if (MODE == 0) {
            *(uint4*)(Xs + sr * 128 + ((sc       ^ (sr & 7)) << 4)) = xa;
            *(uint4*)(Xs + sr * 128 + (((sc + 1) ^ (sr & 7)) << 4)) = xb2;
        } else {
            #pragma unroll
            for (int s = 0; s < 2; ++s) {
                const int f = w * 128 + s * 64 + lane;
                const int r = f >> 3, sl = f & 7;
                gload_lds16(&Xb[(size_t)(row0 + r) * DM + k0 + ((sl ^ (r & 7)) << 3)],
                            Xs + w * 2048 + s * 1024);
            }
        }
        #pragma unroll
        for (int s = 0; s < 2; ++s) {
            const int f = w * 128 + s * 64 + lane;
            const int r = f >> 3, sl = f & 7;
            gload_lds16(&W[(size_t)(col0 + r) * DM + k0 + ((sl ^ (r & 7)) << 3)],
                        Ws + w * 2048 + s * 1024);
        }
        __syncthreads();                   // drains vmcnt(0)+lgkm(0): tiles ready

        #pragma unroll
        for (int kk = 0; kk < 2; ++kk) {
            bf16x8 xf[4], wf[2];
            #pragma unroll
            for (int m = 0; m < 4; ++m) {
                const int r = wr * 64 + m * 16 + l15;
                xf[m] = *(const bf16x8*)(Xs + r * 128 + ((((kk << 2) + lhi) ^ (r & 7)) << 4));
            }
            #pragma unroll
            for (int n = 0; n < 2; ++n) {
                const int r = wc * 32 + n * 16 + l15;
                wf[n] = *(const bf16x8*)(Ws + r * 128 + ((((kk << 2) + lhi) ^ (r & 7)) << 4));
            }
            #pragma unroll
            for (int m = 0; m < 4; ++m)
                #pragma unroll
                for (int n = 0; n < 2; ++n)
                    acc[m][n] = __builtin_amdgcn_mfma_f32_16x16x32_bf16(wf[n], xf[m], acc[m][n], 0, 0, 0);
        }
    }

    // epilogue: lane -> row r=l15(+frag), 4 consecutive channels c
    const float osc = (MODE == 0 && z == 0) ? 0.125f : 1.0f;
    #pragma unroll
    for (int m = 0; m < 4; ++m) {
        const int r = row0 + wr * 64 + m * 16 + l15;
        #pragma unroll
        for (int n = 0; n < 2; ++n) {
            const int cb = col0 + wc * 32 + n * 16 + lhi * 4;
            if (MODE == 0) {
                bf16x4 o4;
                o4[0] = (__bf16)(acc[m][n][0] * osc);
                o4[1] = (__bf16)(acc[m][n][1] * osc);
                o4[2] = (__bf16)(acc[m][n][2] * osc);
                o4[3] = (__bf16)(acc[m][n][3] * osc);
                const int bb = r >> 12, srow = r & 4095;
                const int hh = cb >> 6, dk = cb & 63;
                *(bf16x4*)&Yb[(((size_t)(bb * NHEAD + hh)) * S_LEN + srow) * DKH + dk] = o4;
            } else {
                *(float4*)&Yf[(size_t)r * DM + cb] = *(float4*)&acc[m][n];
            }
        }
    }
}

// ---------------------------------------------------------------------------
// Flash attention: swapped-operand MFMA, in-register softmax, double-buffered
// K/V LDS, ONE barrier per tile, K via global_load_lds, setprio on MFMA.
// 512 thr = 8 waves, 128 q-rows/block (lane owns q-row l15 of its wave's 16).
// LDS 48KB: [Ks0|Vt0|Ks1|Vt1|Ps(8x2KB wave-private)].
// ---------------------------------------------------------------------------
__global__ __launch_bounds__(512, 4)
void attn_mfma(const __bf16* __restrict__ Q, const __bf16* __restrict__ K,
               const __bf16* __restrict__ V, const u64* __restrict__ bits,
               __bf16* __restrict__ ctx)
{
    __shared__ __align__(16) char lds[49152];

    const int tid  = threadIdx.x;
    const int lane = tid & 63;
    const int w    = tid >> 6;
    const int l15  = lane & 15;
    const int lhi  = lane >> 4;
    const int q0   = blockIdx.x << 7;
    const int h    = blockIdx.y;
    const int b    = blockIdx.z;

    const __bf16* Qb = Q + (size_t)(b * NHEAD + h) * S_LEN * DKH;
    const __bf16* Kb = K + (size_t)(b * NHEAD + h) * S_LEN * DKH;
    const __bf16* Vb = V + (size_t)(b * NHEAD + h) * S_LEN * DKH;

    const int qrow = q0 + w * 16 + l15;
    const u64* Mb = bits + (size_t)b * (S_LEN * (S_LEN / 64)) + (size_t)qrow * 64;

    const bf16x8 qa0 = *(const bf16x8*)&Qb[(size_t)qrow * DKH + lhi * 8];
    const bf16x8 qa1 = *(const bf16x8*)&Qb[(size_t)qrow * DKH + 32 + lhi * 8];

    char* psb = lds + 32768 + w * 2048;    // wave-private P scratch

    f32x4 o[4];
    float m_r = MINIT, l_r = 0.f;
    #pragma unroll
    for (int dt = 0; dt < 4; ++dt) o[dt] = (f32x4){0.f, 0.f, 0.f, 0.f};

    const int krow = tid >> 3, kslot = tid & 7;     // K staging map
    const int vj   = tid & 63, vd0 = (tid >> 6) * 8; // V staging map

    // prologue: stage tile 0 into buffer 0
    gload_lds16(&Kb[(size_t)krow * DKH + ((kslot ^ (krow & 7)) << 3)],
                lds + w * 1024);
    {
        const uint4 v0 = *(const uint4*)&Vb[(size_t)vj * DKH + vd0];
        char* Vt = lds + 8192;
        const __bf16* vr = (const __bf16*)&v0;
        #pragma unroll
        for (int i = 0; i < 8; ++i) {
            const int d = vd0 + i;
            *(__bf16*)(Vt + ((d * 128 + vj * 2) ^ ((d & 7) << 4))) = vr[i];
        }
    }
    u64 mcur = Mb[0];
    __syncthreads();

    for (int t = 0; t < NT; ++t) {
        const int c  = t & 1;
        const int tn = (t + 1 < NT) ? (t + 1) : t;

        // issue next tile's loads now; they land during this tile's compute
        gload_lds16(&Kb[(size_t)((tn << 6) + krow) * DKH + ((kslot ^ (krow & 7)) << 3)],
                    lds + (c ^ 1) * 16384 + w * 1024);
        const uint4 vnxt = *(const uint4*)&Vb[(size_t)((tn << 6) + vj) * DKH + vd0];
        const u64   mnxt = Mb[tn];

        const char* Ksb = lds + c * 16384;
        const char* Vtb = Ksb + 8192;

        // ---- QK^T (swapped): s[tt] rows tt*16..+15 of S^T, col q=l15 ----
        f32x4 s[4];
        __builtin_amdgcn_s_setprio(1);
        #pragma unroll
        for (int tt = 0; tt < 4; ++tt) {
            const int kr  = tt * 16 + l15;
            const int off = kr * 128 + ((lhi ^ (kr & 7)) << 4);
            const bf16x8 kb0 = *(const bf16x8*)(Ksb + off);
            const bf16x8 kb1 = *(const bf16x8*)(Ksb + (off ^ 64));
            f32x4 zz = (f32x4){0.f, 0.f, 0.f, 0.f};
            zz    = __builtin_amdgcn_mfma_f32_16x16x32_bf16(kb0, qa0, zz, 0, 0, 0);
            s[tt] = __builtin_amdgcn_mfma_f32_16x16x32_bf16(kb1, qa1, zz, 0, 0, 0);
        }
        __builtin_amdgcn_s_setprio(0);

        // ---- mask + in-register online softmax ----
        const unsigned int lo = (unsigned int)mcur, hi = (unsigned int)(mcur >> 32);
        unsigned int shf[4];
        shf[0] = lo >> (lhi << 2);
        shf[1] = lo >> (16 + (lhi << 2));
        shf[2] = hi >> (lhi << 2);
        shf[3] = hi >> (16 + (lhi << 2));

        float pv[4][4];
        #pragma unroll
        for (int tt = 0; tt < 4; ++tt)
            #pragma unroll
            for (int r = 0; r < 4; ++r)
                pv[tt][r] = ((shf[tt] >> r) & 1) ? NEG_BIG : s[tt][r];

        float tmax = pv[0][0];
        #pragma unroll
        for (int tt = 0; tt < 4; ++tt)
            #pragma unroll
            for (int r = 0; r < 4; ++r)
                tmax = fmaxf(tmax, pv[tt][r]);
        tmax = fmaxf(tmax, __shfl_xor(tmax, 16));
        tmax = fmaxf(tmax, __shfl_xor(tmax, 32));

        if (!__all(tmax <= m_r + 8.f)) {   // defer-max (T13)
            const float newm  = fmaxf(m_r, tmax);
            const float alpha = __expf(m_r - newm);
            m_r = newm;
            l_r *= alpha;
            #pragma unroll
            for (int dt = 0; dt < 4; ++dt) {
                o[dt][0] *= alpha; o[dt][1] *= alpha;
                o[dt][2] *= alpha; o[dt][3] *= alpha;
            }
        }

        float rsum = 0.f;
        #pragma unroll
        for (int tt = 0; tt < 4; ++tt)
            #pragma unroll
            for (int r = 0; r < 4; ++r) {
                pv[tt][r] = __expf(pv[tt][r] - m_r);
                rsum += pv[tt][r];
            }
        rsum += __shfl_xor(rsum, 16);
        rsum += __shfl_xor(rsum, 32);
        l_r += rsum;

        // ---- P -> bf16 via wave-private LDS (no barrier needed) ----
        #pragma unroll
        for (int tt = 0; tt < 4; ++tt)
            #pragma unroll
            for (int cc = 0; cc < 2; ++cc) {
                union { __bf16 h2[2]; unsigned int u; } pk;
                pk.h2[0] = (__bf16)pv[tt][2 * cc];
                pk.h2[1] = (__bf16)pv[tt][2 * cc + 1];
                const int kbyte = tt * 32 + (lhi << 3) + (cc << 2);
                const int off = l15 * 128
                              + (((kbyte >> 4) ^ (l15 & 7)) << 4) + (kbyte & 15);
                *(unsigned int*)(psb + off) = pk.u;
            }
        const int poff = l15 * 128 + ((lhi ^ (l15 & 7)) << 4);
        const bf16x8 pb0 = *(const bf16x8*)(psb + poff);
        const bf16x8 pb1 = *(const bf16x8*)(psb + (poff ^ 64));

        // ---- PV (swapped): o[dt] rows d=dt*16..+15 of O^T, col q=l15 ----
        __builtin_amdgcn_s_setprio(1);
        #pragma unroll
        for (int dt = 0; dt < 4; ++dt) {
            const int vrow = dt * 16 + l15;
            const int voff = vrow * 128 + ((lhi ^ (vrow & 7)) << 4);
            const bf16x8 vb0 = *(const bf16x8*)(Vtb + voff);
            const bf16x8 vb1 = *(const bf16x8*)(Vtb + (voff ^ 64));
            o[dt] = __builtin_amdgcn_mfma_f32_16x16x32_bf16(vb0, pb0, o[dt], 0, 0, 0);
            o[dt] = __builtin_amdgcn_mfma_f32_16x16x32_bf16(vb1, pb1, o[dt], 0, 0, 0);
        }
        __builtin_amdgcn_s_setprio(0);

        // ---- stage V(t+1) into the other buffer; single barrier ----
        {
            char* Vt = lds + (c ^ 1) * 16384 + 8192;
            const __bf16* vr = (const __bf16*)&vnxt;
            #pragma unroll
            for (int i = 0; i < 8; ++i) {
                const int d = vd0 + i;
                *(__bf16*)(Vt + ((d * 128 + vj * 2) ^ ((d & 7) << 4))) = vr[i];
            }
        }
        __syncthreads();   // drains vmcnt(0)+lgkm(0): next tile fully staged
        mcur = mnxt;
    }

    // epilogue: O^T[q=l15][d=dt*16+lhi*4+r] -> ctx bf16 [B,S,512]
    const float inv = 1.f / l_r;
    #pragma unroll
    for (int dt = 0; dt < 4; ++dt) {
        bf16x4 ov;
        ov[0] = (__bf16)(o[dt][0] * inv);
        ov[1] = (__bf16)(o[dt][1] * inv);
        ov[2] = (__bf16)(o[dt][2] * inv);
        ov[3] = (__bf16)(o[dt][3] * inv);
        *(bf16x4*)&ctx[((size_t)b * S_LEN + qrow) * DM + h * DKH + dt * 16 + lhi * 4] = ov;
    }
}

// ---------------------------------------------------------------------------
extern "C" void kernel_launch(void* const* d_in, const int* in_sizes, int n_in,
                              void* d_out, int out_size, void* d_ws, size_t ws_size,
                              hipStream_t stream)
{
    const float* q    = (const float*)d_in[0];
    const float* k    = (const float*)d_in[1];
    const float* v    = (const float*)d_in[2];
    const int*   mask = (const int*)d_in[3];
    const float* Wq   = (const float*)d_in[4];
    const float* Wk   = (const float*)d_in[5];
    const float* Wv   = (const float*)d_in[6];
    const float* Wo   = (const float*)d_in[7];
    float* out = (float*)d_out;

    // ws: wb bf16 [4][512][512] (2MB) | Qh|Kh|Vh|ctx bf16 (8.39MB each) | bits (4.2MB)
    const size_t per = (size_t)2 * S_LEN * DM;
    __bf16* wb   = (__bf16*)d_ws;
    __bf16* Qh   = wb + (size_t)4 * DM * DM;
    __bf16* Kh   = Qh + per;
    __bf16* Vh   = Kh + per;
    __bf16* ctx  = Vh + per;
    u64*    bits = (u64*)(ctx + per);

    cast_w<<<dim3(512), dim3(256), 0, stream>>>(Wq, Wk, Wv, Wo, wb);

    pack_mask<<<dim3((2 * S_LEN * S_LEN) / 256), dim3(256), 0, stream>>>(mask, bits);

    gemm_mfma<0><<<dim3(64, 4, 3), dim3(512), 0, stream>>>(
        q, k, v, nullptr, wb, Qh, Kh, Vh, nullptr);

    attn_mfma<<<dim3(S_LEN / 128, NHEAD, 2), dim3(512), 0, stream>>>(
        Qh, Kh, Vh, bits, ctx);

    gemm_mfma<1><<<dim3(64, 4, 1), dim3(512), 0, stream>>>(
        nullptr, nullptr, nullptr, ctx, wb + (size_t)3 * DM * DM,
        nullptr, nullptr, nullptr, out);
}